// Round 1
// baseline (246.116 us; speedup 1.0000x reference)
//
#include <hip/hip_runtime.h>

#define B 2
#define N 64
#define D 256
#define H 8
#define DK 32
#define M (B * N * N) // 8192

// ---------------------------------------------------------------------------
// GEMM: C[M,256] = X[M,256] @ W^T + bias   (W is [256,256] row-major [e,d])
// grid (M/64, 4), block 256. 64x64 tile, 4x4 per thread, K-chunk 16.
// LDS stored transposed [k][row] (+pad to 68 -> 16B-aligned rows) so the
// inner loop is two ds_read_b128 per k.
// ---------------------------------------------------------------------------
__global__ __launch_bounds__(256) void gemm_nt(const float* __restrict__ X,
                                               const float* __restrict__ W,
                                               const float* __restrict__ bias,
                                               float* __restrict__ C) {
    __shared__ __align__(16) float XsT[16][68];
    __shared__ __align__(16) float WsT[16][68];
    const int tid = threadIdx.x;
    const int tx = tid & 15;   // col group (4 cols)
    const int ty = tid >> 4;   // row group (4 rows)
    const int row0 = blockIdx.x * 64;
    const int col0 = blockIdx.y * 64;
    const int lr = tid >> 2;        // 0..63 load row
    const int lk = (tid & 3) * 4;   // k offset {0,4,8,12}

    float acc[4][4] = {};

    for (int k0 = 0; k0 < 256; k0 += 16) {
        float4 xa = *(const float4*)&X[(size_t)(row0 + lr) * 256 + k0 + lk];
        float4 wa = *(const float4*)&W[(size_t)(col0 + lr) * 256 + k0 + lk];
        __syncthreads();
        XsT[lk + 0][lr] = xa.x; XsT[lk + 1][lr] = xa.y;
        XsT[lk + 2][lr] = xa.z; XsT[lk + 3][lr] = xa.w;
        WsT[lk + 0][lr] = wa.x; WsT[lk + 1][lr] = wa.y;
        WsT[lk + 2][lr] = wa.z; WsT[lk + 3][lr] = wa.w;
        __syncthreads();
#pragma unroll
        for (int k = 0; k < 16; ++k) {
            float4 a = *(const float4*)&XsT[k][ty * 4];
            float4 b = *(const float4*)&WsT[k][tx * 4];
            acc[0][0] += a.x * b.x; acc[0][1] += a.x * b.y; acc[0][2] += a.x * b.z; acc[0][3] += a.x * b.w;
            acc[1][0] += a.y * b.x; acc[1][1] += a.y * b.y; acc[1][2] += a.y * b.z; acc[1][3] += a.y * b.w;
            acc[2][0] += a.z * b.x; acc[2][1] += a.z * b.y; acc[2][2] += a.z * b.z; acc[2][3] += a.z * b.w;
            acc[3][0] += a.w * b.x; acc[3][1] += a.w * b.y; acc[3][2] += a.w * b.z; acc[3][3] += a.w * b.w;
        }
    }

    const float4 bv = *(const float4*)&bias[col0 + tx * 4];
#pragma unroll
    for (int i = 0; i < 4; ++i) {
        float4 o;
        o.x = acc[i][0] + bv.x; o.y = acc[i][1] + bv.y;
        o.z = acc[i][2] + bv.z; o.w = acc[i][3] + bv.w;
        *(float4*)&C[(size_t)(row0 + ty * 4 + i) * 256 + col0 + tx * 4] = o;
    }
}

// ---------------------------------------------------------------------------
// Scores: per (a,h,b) block: scores[x,y] = sum_d LK[b,x,a,h,d]*RK[b,a,y,h,d]
// scaled by 1/sqrt(DK), masked, written to att[b,h,x,y,a].
// grid (N, H, B), block 256.
// ---------------------------------------------------------------------------
__global__ __launch_bounds__(256) void scores_kernel(const float* __restrict__ LK,
                                                     const float* __restrict__ RK,
                                                     const unsigned char* __restrict__ mask,
                                                     float* __restrict__ att) {
    const int a = blockIdx.x, h = blockIdx.y, b = blockIdx.z;
    __shared__ __align__(16) float LKs[DK][68]; // [d][x]
    __shared__ __align__(16) float RKs[DK][68]; // [d][y]
    const int tid = threadIdx.x;

#pragma unroll
    for (int pass = 0; pass < 2; ++pass) {
        int x = (tid >> 3) + pass * 32;
        int d = (tid & 7) * 4;
        float4 v = *(const float4*)&LK[(((size_t)b * N + x) * N + a) * D + h * DK + d];
        LKs[d + 0][x] = v.x; LKs[d + 1][x] = v.y; LKs[d + 2][x] = v.z; LKs[d + 3][x] = v.w;
        float4 w = *(const float4*)&RK[(((size_t)b * N + a) * N + x) * D + h * DK + d];
        RKs[d + 0][x] = w.x; RKs[d + 1][x] = w.y; RKs[d + 2][x] = w.z; RKs[d + 3][x] = w.w;
    }
    __syncthreads();

    const int tx = tid & 15, ty = tid >> 4;
    float acc[4][4] = {};
#pragma unroll
    for (int d = 0; d < DK; ++d) {
        float4 xa = *(const float4*)&LKs[d][ty * 4];
        float4 yb = *(const float4*)&RKs[d][tx * 4];
        acc[0][0] += xa.x * yb.x; acc[0][1] += xa.x * yb.y; acc[0][2] += xa.x * yb.z; acc[0][3] += xa.x * yb.w;
        acc[1][0] += xa.y * yb.x; acc[1][1] += xa.y * yb.y; acc[1][2] += xa.y * yb.z; acc[1][3] += xa.y * yb.w;
        acc[2][0] += xa.z * yb.x; acc[2][1] += xa.z * yb.y; acc[2][2] += xa.z * yb.z; acc[2][3] += xa.z * yb.w;
        acc[3][0] += xa.w * yb.x; acc[3][1] += xa.w * yb.y; acc[3][2] += xa.w * yb.z; acc[3][3] += xa.w * yb.w;
    }

    const float scale = 0.17677669529663687f; // 1/sqrt(32)
#pragma unroll
    for (int i = 0; i < 4; ++i) {
#pragma unroll
        for (int j = 0; j < 4; ++j) {
            int x = ty * 4 + i, y = tx * 4 + j;
            float s = acc[i][j] * scale;
            if (mask[(((size_t)b * N + x) * N + a) * N + y]) s = -1000.0f;
            att[((((size_t)b * H + h) * N + x) * N + y) * N + a] = s;
        }
    }
}

// ---------------------------------------------------------------------------
// Softmax over last axis (64 contiguous). One wave per row.
// grid 16384, block 256 (= 4 rows/block).
// ---------------------------------------------------------------------------
__global__ __launch_bounds__(256) void softmax_kernel(float* __restrict__ att) {
    const size_t row = (size_t)blockIdx.x * 4 + (threadIdx.x >> 6);
    const int lane = threadIdx.x & 63;
    float* p = att + row * 64;
    float v = p[lane];
    float m = v;
#pragma unroll
    for (int off = 32; off > 0; off >>= 1) m = fmaxf(m, __shfl_xor(m, off));
    float e = __expf(v - m);
    float s = e;
#pragma unroll
    for (int off = 32; off > 0; off >>= 1) s += __shfl_xor(s, off);
    p[lane] = e / s;
}

// ---------------------------------------------------------------------------
// Combine: out[b,x,y,h,d] = sum_a att[b,h,x,y,a] * LV[b,x,a,h,d] * RV[b,a,y,h,d]
// grid (4, 4, B*H): 16x by 16y tile, a-chunks of 8. block 256.
// Thread owns (x_l = tid>>4, dp = tid&15 -> d = {2dp, 2dp+1}), accumulates 16 y.
// ---------------------------------------------------------------------------
__global__ __launch_bounds__(256) void combine_kernel(const float* __restrict__ LV,
                                                      const float* __restrict__ RV,
                                                      const float* __restrict__ att,
                                                      float* __restrict__ xbuf) {
    const int LVSTRIDE = 8 * 32 + 8; // 264: 16B-aligned rows, banks spread
    __shared__ __align__(16) float LVs[16 * 264];     // [x][a*32+d]
    __shared__ __align__(16) float RVs[8 * 16 * 32];  // [a][y][d]
    __shared__ __align__(16) float atts[16][129];     // [x][a*16+y] (+1 pad)

    const int b = blockIdx.z >> 3, h = blockIdx.z & 7;
    const int x0 = blockIdx.x * 16, y0 = blockIdx.y * 16;
    const int tid = threadIdx.x;
    const int x_l = tid >> 4, dp = tid & 15;

    float2 acc[16] = {};

    for (int ac = 0; ac < N; ac += 8) {
        __syncthreads();
        {
            // LV rows (x, a): 128 rows x 32 floats; 2 threads per row
            int row = tid >> 1;
            int x = row >> 3, a = row & 7;
            int q0 = (tid & 1) * 16;
            const float* src = &LV[(((size_t)b * N + x0 + x) * N + ac + a) * D + h * DK + q0];
            float* dst = &LVs[x * LVSTRIDE + a * 32 + q0];
#pragma unroll
            for (int q = 0; q < 4; ++q) *(float4*)&dst[q * 4] = *(const float4*)&src[q * 4];

            // RV rows (a, y): 128 rows x 32 floats
            int aa = row >> 4, y = row & 15;
            const float* src2 = &RV[(((size_t)b * N + ac + aa) * N + y0 + y) * D + h * DK + q0];
            float* dst2 = &RVs[(aa * 16 + y) * 32 + q0];
#pragma unroll
            for (int q = 0; q < 4; ++q) *(float4*)&dst2[q * 4] = *(const float4*)&src2[q * 4];

            // att: thread (x3, y3) loads 8 a-values for its (x,y)
            int x3 = tid >> 4, y3 = tid & 15;
            const float* src3 = &att[((((size_t)b * H + h) * N + x0 + x3) * N + y0 + y3) * N + ac];
            float4 v0 = *(const float4*)&src3[0];
            float4 v1 = *(const float4*)&src3[4];
            atts[x3][0 * 16 + y3] = v0.x; atts[x3][1 * 16 + y3] = v0.y;
            atts[x3][2 * 16 + y3] = v0.z; atts[x3][3 * 16 + y3] = v0.w;
            atts[x3][4 * 16 + y3] = v1.x; atts[x3][5 * 16 + y3] = v1.y;
            atts[x3][6 * 16 + y3] = v1.z; atts[x3][7 * 16 + y3] = v1.w;
        }
        __syncthreads();

#pragma unroll
        for (int a = 0; a < 8; ++a) {
            float2 lv = *(const float2*)&LVs[x_l * LVSTRIDE + a * 32 + 2 * dp];
#pragma unroll
            for (int y = 0; y < 16; ++y) {
                float w = atts[x_l][a * 16 + y];
                float2 rv = *(const float2*)&RVs[(a * 16 + y) * 32 + 2 * dp];
                acc[y].x += (w * lv.x) * rv.x;
                acc[y].y += (w * lv.y) * rv.y;
            }
        }
    }

#pragma unroll
    for (int y = 0; y < 16; ++y) {
        *(float2*)&xbuf[(((size_t)b * N + x0 + x_l) * N + y0 + y) * D + h * DK + 2 * dp] = acc[y];
    }
}

// ---------------------------------------------------------------------------
extern "C" void kernel_launch(void* const* d_in, const int* in_sizes, int n_in,
                              void* d_out, int out_size, void* d_ws, size_t ws_size,
                              hipStream_t stream) {
    const float* state = (const float*)d_in[0];
    const unsigned char* mask = (const unsigned char*)d_in[1];
    const float* W_lk = (const float*)d_in[2];
    const float* b_lk = (const float*)d_in[3];
    const float* W_rk = (const float*)d_in[4];
    const float* b_rk = (const float*)d_in[5];
    const float* W_lv = (const float*)d_in[6];
    const float* b_lv = (const float*)d_in[7];
    const float* W_rv = (const float*)d_in[8];
    const float* b_rv = (const float*)d_in[9];
    const float* W_o = (const float*)d_in[10];
    const float* b_o = (const float*)d_in[11];
    float* out = (float*)d_out;

    float* ws = (float*)d_ws;
    const size_t PROJ = (size_t)M * D; // 2,097,152
    float* LK = ws;
    float* RK = LK + PROJ;
    float* LV = RK + PROJ;
    float* RV = LV + PROJ;
    float* att = RV + PROJ;            // B*H*N*N*N = 4,194,304
    float* xbuf = att + (size_t)B * H * N * N * N;

    gemm_nt<<<dim3(M / 64, 4), 256, 0, stream>>>(state, W_lk, b_lk, LK);
    gemm_nt<<<dim3(M / 64, 4), 256, 0, stream>>>(state, W_rk, b_rk, RK);
    gemm_nt<<<dim3(M / 64, 4), 256, 0, stream>>>(state, W_lv, b_lv, LV);
    gemm_nt<<<dim3(M / 64, 4), 256, 0, stream>>>(state, W_rv, b_rv, RV);
    scores_kernel<<<dim3(N, H, B), 256, 0, stream>>>(LK, RK, mask, att);
    softmax_kernel<<<(B * H * N * N) / 4, 256, 0, stream>>>(att);
    combine_kernel<<<dim3(4, 4, B * H), 256, 0, stream>>>(LV, RV, att, xbuf);
    gemm_nt<<<dim3(M / 64, 4), 256, 0, stream>>>(xbuf, W_o, b_o, out);
}

// Round 2
// 204.337 us; speedup vs baseline: 1.2045x; 1.2045x over previous
//
#include <hip/hip_runtime.h>

#define B 2
#define N 64
#define D 256
#define H 8
#define DK 32
#define M (B * N * N) // 8192

// ---------------------------------------------------------------------------
// GEMM tile body: C[M,256] = X[M,256] @ W^T + bias (W row-major [e,d]).
// 64x64 tile, 4x4 per thread, K-chunk 16, transposed LDS for ds_read_b128.
// Uses blockIdx.x (row tile), blockIdx.y (col tile).
// ---------------------------------------------------------------------------
__device__ __forceinline__ void gemm_tile(const float* __restrict__ X,
                                          const float* __restrict__ W,
                                          const float* __restrict__ bias,
                                          float* __restrict__ C) {
    __shared__ __align__(16) float XsT[16][68];
    __shared__ __align__(16) float WsT[16][68];
    const int tid = threadIdx.x;
    const int tx = tid & 15;   // col group (4 cols)
    const int ty = tid >> 4;   // row group (4 rows)
    const int row0 = blockIdx.x * 64;
    const int col0 = blockIdx.y * 64;
    const int lr = tid >> 2;        // 0..63 load row
    const int lk = (tid & 3) * 4;   // k offset {0,4,8,12}

    float acc[4][4] = {};

    for (int k0 = 0; k0 < 256; k0 += 16) {
        float4 xa = *(const float4*)&X[(size_t)(row0 + lr) * 256 + k0 + lk];
        float4 wa = *(const float4*)&W[(size_t)(col0 + lr) * 256 + k0 + lk];
        __syncthreads();
        XsT[lk + 0][lr] = xa.x; XsT[lk + 1][lr] = xa.y;
        XsT[lk + 2][lr] = xa.z; XsT[lk + 3][lr] = xa.w;
        WsT[lk + 0][lr] = wa.x; WsT[lk + 1][lr] = wa.y;
        WsT[lk + 2][lr] = wa.z; WsT[lk + 3][lr] = wa.w;
        __syncthreads();
#pragma unroll
        for (int k = 0; k < 16; ++k) {
            float4 a = *(const float4*)&XsT[k][ty * 4];
            float4 b = *(const float4*)&WsT[k][tx * 4];
            acc[0][0] += a.x * b.x; acc[0][1] += a.x * b.y; acc[0][2] += a.x * b.z; acc[0][3] += a.x * b.w;
            acc[1][0] += a.y * b.x; acc[1][1] += a.y * b.y; acc[1][2] += a.y * b.z; acc[1][3] += a.y * b.w;
            acc[2][0] += a.z * b.x; acc[2][1] += a.z * b.y; acc[2][2] += a.z * b.z; acc[2][3] += a.z * b.w;
            acc[3][0] += a.w * b.x; acc[3][1] += a.w * b.y; acc[3][2] += a.w * b.z; acc[3][3] += a.w * b.w;
        }
    }

    const float4 bv = *(const float4*)&bias[col0 + tx * 4];
#pragma unroll
    for (int i = 0; i < 4; ++i) {
        float4 o;
        o.x = acc[i][0] + bv.x; o.y = acc[i][1] + bv.y;
        o.z = acc[i][2] + bv.z; o.w = acc[i][3] + bv.w;
        *(float4*)&C[(size_t)(row0 + ty * 4 + i) * 256 + col0 + tx * 4] = o;
    }
}

__global__ __launch_bounds__(256) void gemm_nt(const float* __restrict__ X,
                                               const float* __restrict__ W,
                                               const float* __restrict__ bias,
                                               float* __restrict__ C) {
    gemm_tile(X, W, bias, C);
}

// Fused 4-way projection: blockIdx.z selects which {W,b,out} to use.
__global__ __launch_bounds__(256) void gemm_proj4(const float* __restrict__ X,
                                                  const float* __restrict__ W0, const float* __restrict__ W1,
                                                  const float* __restrict__ W2, const float* __restrict__ W3,
                                                  const float* __restrict__ b0, const float* __restrict__ b1,
                                                  const float* __restrict__ b2, const float* __restrict__ b3,
                                                  float* __restrict__ O0, float* __restrict__ O1,
                                                  float* __restrict__ O2, float* __restrict__ O3) {
    const float* Ws[4] = {W0, W1, W2, W3};
    const float* bs[4] = {b0, b1, b2, b3};
    float* Os[4] = {O0, O1, O2, O3};
    const int z = blockIdx.z;
    gemm_tile(X, Ws[z], bs[z], Os[z]);
}

// ---------------------------------------------------------------------------
// Scores: per (a,h,b) block: scores[x,y] = sum_d LK[b,x,a,h,d]*RK[b,a,y,h,d]
// scaled by 1/sqrt(DK), masked, written to att[b,h,a,x,y] — the block's
// 64x64 tile is a CONTIGUOUS 16 KB region -> fully coalesced float4 stores.
// grid (N, H, B), block 256.
// ---------------------------------------------------------------------------
__global__ __launch_bounds__(256) void scores_kernel(const float* __restrict__ LK,
                                                     const float* __restrict__ RK,
                                                     const unsigned char* __restrict__ mask,
                                                     float* __restrict__ att) {
    const int a = blockIdx.x, h = blockIdx.y, b = blockIdx.z;
    __shared__ __align__(16) float LKs[DK][68]; // [d][x]
    __shared__ __align__(16) float RKs[DK][68]; // [d][y]
    const int tid = threadIdx.x;

#pragma unroll
    for (int pass = 0; pass < 2; ++pass) {
        int x = (tid >> 3) + pass * 32;
        int d = (tid & 7) * 4;
        float4 v = *(const float4*)&LK[(((size_t)b * N + x) * N + a) * D + h * DK + d];
        LKs[d + 0][x] = v.x; LKs[d + 1][x] = v.y; LKs[d + 2][x] = v.z; LKs[d + 3][x] = v.w;
        float4 w = *(const float4*)&RK[(((size_t)b * N + a) * N + x) * D + h * DK + d];
        RKs[d + 0][x] = w.x; RKs[d + 1][x] = w.y; RKs[d + 2][x] = w.z; RKs[d + 3][x] = w.w;
    }
    __syncthreads();

    const int tx = tid & 15, ty = tid >> 4;
    float acc[4][4] = {};
#pragma unroll
    for (int d = 0; d < DK; ++d) {
        float4 xa = *(const float4*)&LKs[d][ty * 4];
        float4 yb = *(const float4*)&RKs[d][tx * 4];
        acc[0][0] += xa.x * yb.x; acc[0][1] += xa.x * yb.y; acc[0][2] += xa.x * yb.z; acc[0][3] += xa.x * yb.w;
        acc[1][0] += xa.y * yb.x; acc[1][1] += xa.y * yb.y; acc[1][2] += xa.y * yb.z; acc[1][3] += xa.y * yb.w;
        acc[2][0] += xa.z * yb.x; acc[2][1] += xa.z * yb.y; acc[2][2] += xa.z * yb.z; acc[2][3] += xa.z * yb.w;
        acc[3][0] += xa.w * yb.x; acc[3][1] += xa.w * yb.y; acc[3][2] += xa.w * yb.z; acc[3][3] += xa.w * yb.w;
    }

    const float scale = 0.17677669529663687f; // 1/sqrt(32)
    float* tile = &att[(((size_t)(b * H + h) * N + a) * N) * N]; // + x*64 + y
#pragma unroll
    for (int i = 0; i < 4; ++i) {
        const int x = ty * 4 + i;
        uchar4 mk = *(const uchar4*)&mask[(((size_t)b * N + x) * N + a) * N + tx * 4];
        float4 o;
        o.x = mk.x ? -1000.0f : acc[i][0] * scale;
        o.y = mk.y ? -1000.0f : acc[i][1] * scale;
        o.z = mk.z ? -1000.0f : acc[i][2] * scale;
        o.w = mk.w ? -1000.0f : acc[i][3] * scale;
        *(float4*)&tile[x * 64 + tx * 4] = o;
    }
}

// ---------------------------------------------------------------------------
// Softmax over a (stride N*N in [b,h,a,x,y] layout). One thread per (x,y);
// 64 values held in registers. Lane-coalesced loads/stores (1 KB per wave
// per a-slice). grid B*H*16, block 256.
// ---------------------------------------------------------------------------
__global__ __launch_bounds__(256) void softmax_a(float* __restrict__ att) {
    const int bh = blockIdx.x >> 4;
    const int chunk = blockIdx.x & 15;
    float* base = att + (size_t)bh * (N * N * N) + chunk * 256 + threadIdx.x;

    float v[64];
    float m = -1e30f;
#pragma unroll
    for (int a = 0; a < 64; ++a) {
        v[a] = base[(size_t)a * (N * N)];
        m = fmaxf(m, v[a]);
    }
    float s = 0.0f;
#pragma unroll
    for (int a = 0; a < 64; ++a) {
        v[a] = __expf(v[a] - m);
        s += v[a];
    }
    const float inv = 1.0f / s;
#pragma unroll
    for (int a = 0; a < 64; ++a) {
        base[(size_t)a * (N * N)] = v[a] * inv;
    }
}

// ---------------------------------------------------------------------------
// Combine: out[b,x,y,h,d] = sum_a att[b,h,a,x,y] * LV[b,x,a,h,d] * RV[b,a,y,h,d]
// grid (4, 4, B*H): 16x by 16y tile, a-chunks of 8. block 256.
// Thread owns (x_l = tid>>4, dp = tid&15 -> d = {2dp, 2dp+1}), accumulates 16 y.
// ---------------------------------------------------------------------------
__global__ __launch_bounds__(256) void combine_kernel(const float* __restrict__ LV,
                                                      const float* __restrict__ RV,
                                                      const float* __restrict__ att,
                                                      float* __restrict__ xbuf) {
    const int LVSTRIDE = 8 * 32 + 8; // 264: 16B-aligned rows, banks spread
    __shared__ __align__(16) float LVs[16 * 264];     // [x][a*32+d]
    __shared__ __align__(16) float RVs[8 * 16 * 32];  // [a][y][d]
    __shared__ __align__(16) float atts[16][132];     // [x][a*16+y] (+pad, 16B-aligned rows)

    const int bh = blockIdx.z;
    const int b = bh >> 3, h = bh & 7;
    const int x0 = blockIdx.x * 16, y0 = blockIdx.y * 16;
    const int tid = threadIdx.x;
    const int x_l = tid >> 4, dp = tid & 15;

    float2 acc[16] = {};

    for (int ac = 0; ac < N; ac += 8) {
        __syncthreads();
        {
            // LV rows (x, a): 128 rows x 32 floats; 2 threads per row
            int row = tid >> 1;
            int x = row >> 3, a = row & 7;
            int q0 = (tid & 1) * 16;
            const float* src = &LV[(((size_t)b * N + x0 + x) * N + ac + a) * D + h * DK + q0];
            float* dst = &LVs[x * LVSTRIDE + a * 32 + q0];
#pragma unroll
            for (int q = 0; q < 4; ++q) *(float4*)&dst[q * 4] = *(const float4*)&src[q * 4];

            // RV rows (a, y): 128 rows x 32 floats
            int aa = row >> 4, y = row & 15;
            const float* src2 = &RV[(((size_t)b * N + ac + aa) * N + y0 + y) * D + h * DK + q0];
            float* dst2 = &RVs[(aa * 16 + y) * 32 + q0];
#pragma unroll
            for (int q = 0; q < 4; ++q) *(float4*)&dst2[q * 4] = *(const float4*)&src2[q * 4];

            // att[b,h,a,x,y]: thread (al, xl, half) loads 8 y-values for (a,x)
            int al = tid >> 5;          // 0..7
            int xl = (tid >> 1) & 15;   // 0..15
            int half = tid & 1;         // 0..1 -> y offset 0 / 8
            const float* src3 = &att[(((size_t)bh * N + ac + al) * N + x0 + xl) * N + y0 + half * 8];
            float4 v0 = *(const float4*)&src3[0];
            float4 v1 = *(const float4*)&src3[4];
            *(float4*)&atts[xl][al * 16 + half * 8] = v0;
            *(float4*)&atts[xl][al * 16 + half * 8 + 4] = v1;
        }
        __syncthreads();

#pragma unroll
        for (int a = 0; a < 8; ++a) {
            float2 lv = *(const float2*)&LVs[x_l * LVSTRIDE + a * 32 + 2 * dp];
#pragma unroll
            for (int y = 0; y < 16; ++y) {
                float w = atts[x_l][a * 16 + y];
                float2 rv = *(const float2*)&RVs[(a * 16 + y) * 32 + 2 * dp];
                acc[y].x += (w * lv.x) * rv.x;
                acc[y].y += (w * lv.y) * rv.y;
            }
        }
    }

#pragma unroll
    for (int y = 0; y < 16; ++y) {
        *(float2*)&xbuf[(((size_t)b * N + x0 + x_l) * N + y0 + y) * D + h * DK + 2 * dp] = acc[y];
    }
}

// ---------------------------------------------------------------------------
extern "C" void kernel_launch(void* const* d_in, const int* in_sizes, int n_in,
                              void* d_out, int out_size, void* d_ws, size_t ws_size,
                              hipStream_t stream) {
    const float* state = (const float*)d_in[0];
    const unsigned char* mask = (const unsigned char*)d_in[1];
    const float* W_lk = (const float*)d_in[2];
    const float* b_lk = (const float*)d_in[3];
    const float* W_rk = (const float*)d_in[4];
    const float* b_rk = (const float*)d_in[5];
    const float* W_lv = (const float*)d_in[6];
    const float* b_lv = (const float*)d_in[7];
    const float* W_rv = (const float*)d_in[8];
    const float* b_rv = (const float*)d_in[9];
    const float* W_o = (const float*)d_in[10];
    const float* b_o = (const float*)d_in[11];
    float* out = (float*)d_out;

    float* ws = (float*)d_ws;
    const size_t PROJ = (size_t)M * D; // 2,097,152
    float* LK = ws;
    float* RK = LK + PROJ;
    float* LV = RK + PROJ;
    float* RV = LV + PROJ;
    float* att = RV + PROJ;            // B*H*N*N*N = 4,194,304, layout [b,h,a,x,y]
    float* xbuf = att + (size_t)B * H * N * N * N;

    gemm_proj4<<<dim3(M / 64, 4, 4), 256, 0, stream>>>(state,
        W_lk, W_rk, W_lv, W_rv, b_lk, b_rk, b_lv, b_rv, LK, RK, LV, RV);
    scores_kernel<<<dim3(N, H, B), 256, 0, stream>>>(LK, RK, mask, att);
    softmax_a<<<B * H * 16, 256, 0, stream>>>(att);
    combine_kernel<<<dim3(4, 4, B * H), 256, 0, stream>>>(LV, RV, att, xbuf);
    gemm_nt<<<dim3(M / 64, 4), 256, 0, stream>>>(xbuf, W_o, b_o, out);
}

// Round 3
// 152.913 us; speedup vs baseline: 1.6095x; 1.3363x over previous
//
#include <hip/hip_runtime.h>

#define B 2
#define N 64
#define D 256
#define H 8
#define DK 32
#define M (B * N * N) // 8192

typedef __attribute__((ext_vector_type(8))) short bf16x8;
typedef __attribute__((ext_vector_type(4))) float f32x4;

// fused projection buffer column offsets (in floats, row stride 1024)
#define OFF_LK 0
#define OFF_RK 256
#define OFF_LV 512
#define OFF_RV 768

__device__ __forceinline__ ushort f2b(float f) {
    union { float f; unsigned u; } v; v.f = f;
    unsigned r = v.u + 0x7fffu + ((v.u >> 16) & 1u); // RNE
    return (ushort)(r >> 16);
}

// ---------------------------------------------------------------------------
// Cast: state (2,097,152 f32) -> bf16; 5 weights -> Wcat[1280][256] bf16
// (rows 0..255 W_lk, 256.. W_rk, 512.. W_lv, 768.. W_rv, 1024.. W_o);
// biases -> bias_cat[1280] f32. grid 2368 x 256, 4 elems/thread.
// ---------------------------------------------------------------------------
__global__ __launch_bounds__(256) void cast_all(const float* __restrict__ state,
                                                const float* __restrict__ W_lk, const float* __restrict__ W_rk,
                                                const float* __restrict__ W_lv, const float* __restrict__ W_rv,
                                                const float* __restrict__ W_o,
                                                const float* __restrict__ b_lk, const float* __restrict__ b_rk,
                                                const float* __restrict__ b_lv, const float* __restrict__ b_rv,
                                                const float* __restrict__ b_o,
                                                ushort* __restrict__ state_bf,
                                                ushort* __restrict__ Wcat,
                                                float* __restrict__ bias_cat) {
    const int gid = blockIdx.x * 256 + threadIdx.x;
    const float* Ws[5] = {W_lk, W_rk, W_lv, W_rv, W_o};
    const float* bs[5] = {b_lk, b_rk, b_lv, b_rv, b_o};

    if (gid < 1280) bias_cat[gid] = bs[gid >> 8][gid & 255];

    if (gid < 524288) {
        float4 v = *(const float4*)&state[(size_t)gid * 4];
        ushort4 o = {f2b(v.x), f2b(v.y), f2b(v.z), f2b(v.w)};
        *(ushort4*)&state_bf[(size_t)gid * 4] = o;
    } else {
        int u = gid - 524288;            // 0..81919
        int row = u >> 6;                // 0..1279 (Wcat row)
        int k4 = (u & 63) * 4;           // 0..252
        const float* W = Ws[row >> 8];
        float4 v = *(const float4*)&W[(size_t)(row & 255) * 256 + k4];
        ushort4 o = {f2b(v.x), f2b(v.y), f2b(v.z), f2b(v.w)};
        *(ushort4*)&Wcat[(size_t)row * 256 + k4] = o;
    }
}

// ---------------------------------------------------------------------------
// bf16 MFMA GEMM: C[rows, ldc] = A[rows,256]bf16 @ Bw[cols,256]bf16^T + bias,
// fp32 out. 128x128 block tile, 4 waves (2x2), each wave 64x64 via 4x4 MFMA
// 16x16x32 frags. BK=32, K=256. LDS rows padded to 56 bf16 (112 B: 16B-aligned,
// 28-float stride -> 2-way-max bank aliasing on frag reads, which is free).
// ---------------------------------------------------------------------------
#define LDK 56

__global__ __launch_bounds__(256) void gemm_mfma(const ushort* __restrict__ A,
                                                 const ushort* __restrict__ Bw,
                                                 const float* __restrict__ bias,
                                                 float* __restrict__ C, int ldc) {
    __shared__ __align__(16) ushort As[128 * LDK];
    __shared__ __align__(16) ushort Bs[128 * LDK];
    const int tid = threadIdx.x;
    const int lane = tid & 63;
    const int wave = tid >> 6;
    const int wm = (wave & 1) * 64;
    const int wn = (wave >> 1) * 64;
    const int row0 = blockIdx.x * 128;
    const int col0 = blockIdx.y * 128;

    const int srow = tid >> 2;       // 0..63 staging row
    const int skq = (tid & 3) * 8;   // bf16 k-offset 0,8,16,24

    const int fr = lane & 15;        // fragment row
    const int fk = (lane >> 4) * 8;  // fragment k offset (quad*8)

    f32x4 acc[4][4] = {};

    for (int k0 = 0; k0 < 256; k0 += 32) {
        float4 av0 = *(const float4*)&A[(size_t)(row0 + srow) * 256 + k0 + skq];
        float4 av1 = *(const float4*)&A[(size_t)(row0 + 64 + srow) * 256 + k0 + skq];
        float4 bv0 = *(const float4*)&Bw[(size_t)(col0 + srow) * 256 + k0 + skq];
        float4 bv1 = *(const float4*)&Bw[(size_t)(col0 + 64 + srow) * 256 + k0 + skq];
        __syncthreads();
        *(float4*)&As[srow * LDK + skq] = av0;
        *(float4*)&As[(64 + srow) * LDK + skq] = av1;
        *(float4*)&Bs[srow * LDK + skq] = bv0;
        *(float4*)&Bs[(64 + srow) * LDK + skq] = bv1;
        __syncthreads();

        bf16x8 af[4], bf[4];
#pragma unroll
        for (int i = 0; i < 4; ++i)
            af[i] = *(const bf16x8*)&As[(wm + i * 16 + fr) * LDK + fk];
#pragma unroll
        for (int j = 0; j < 4; ++j)
            bf[j] = *(const bf16x8*)&Bs[(wn + j * 16 + fr) * LDK + fk];
#pragma unroll
        for (int i = 0; i < 4; ++i)
#pragma unroll
            for (int j = 0; j < 4; ++j)
                acc[i][j] = __builtin_amdgcn_mfma_f32_16x16x32_bf16(af[i], bf[j], acc[i][j], 0, 0, 0);
    }

    // Epilogue: D[row][col]: row = (lane>>4)*4 + reg, col = lane&15.
#pragma unroll
    for (int j = 0; j < 4; ++j) {
        const int col = col0 + wn + j * 16 + (lane & 15);
        const float bv = bias[col];
#pragma unroll
        for (int i = 0; i < 4; ++i) {
            const int rbase = row0 + wm + i * 16 + (lane >> 4) * 4;
#pragma unroll
            for (int r = 0; r < 4; ++r)
                C[(size_t)(rbase + r) * ldc + col] = acc[i][j][r] + bv;
        }
    }
}

// ---------------------------------------------------------------------------
// Scores: per (a,h,b) block: scores[x,y] = sum_d LK[b,x,a,h,d]*RK[b,a,y,h,d]
// LK/RK read from fused P[8192][1024]. Output att[b,h,a,x,y]: contiguous
// 16 KB tile per block -> coalesced float4 stores. grid (N, H, B), block 256.
// ---------------------------------------------------------------------------
__global__ __launch_bounds__(256) void scores_kernel(const float* __restrict__ P,
                                                     const unsigned char* __restrict__ mask,
                                                     float* __restrict__ att) {
    const int a = blockIdx.x, h = blockIdx.y, b = blockIdx.z;
    __shared__ __align__(16) float LKs[DK][68]; // [d][x]
    __shared__ __align__(16) float RKs[DK][68]; // [d][y]
    const int tid = threadIdx.x;

#pragma unroll
    for (int pass = 0; pass < 2; ++pass) {
        int x = (tid >> 3) + pass * 32;
        int d = (tid & 7) * 4;
        float4 v = *(const float4*)&P[(((size_t)b * N + x) * N + a) * 1024 + OFF_LK + h * DK + d];
        LKs[d + 0][x] = v.x; LKs[d + 1][x] = v.y; LKs[d + 2][x] = v.z; LKs[d + 3][x] = v.w;
        float4 w = *(const float4*)&P[(((size_t)b * N + a) * N + x) * 1024 + OFF_RK + h * DK + d];
        RKs[d + 0][x] = w.x; RKs[d + 1][x] = w.y; RKs[d + 2][x] = w.z; RKs[d + 3][x] = w.w;
    }
    __syncthreads();

    const int tx = tid & 15, ty = tid >> 4;
    float acc[4][4] = {};
#pragma unroll
    for (int d = 0; d < DK; ++d) {
        float4 xa = *(const float4*)&LKs[d][ty * 4];
        float4 yb = *(const float4*)&RKs[d][tx * 4];
        acc[0][0] += xa.x * yb.x; acc[0][1] += xa.x * yb.y; acc[0][2] += xa.x * yb.z; acc[0][3] += xa.x * yb.w;
        acc[1][0] += xa.y * yb.x; acc[1][1] += xa.y * yb.y; acc[1][2] += xa.y * yb.z; acc[1][3] += xa.y * yb.w;
        acc[2][0] += xa.z * yb.x; acc[2][1] += xa.z * yb.y; acc[2][2] += xa.z * yb.z; acc[2][3] += xa.z * yb.w;
        acc[3][0] += xa.w * yb.x; acc[3][1] += xa.w * yb.y; acc[3][2] += xa.w * yb.z; acc[3][3] += xa.w * yb.w;
    }

    const float scale = 0.17677669529663687f; // 1/sqrt(32)
    float* tile = &att[(((size_t)(b * H + h) * N + a) * N) * N]; // + x*64 + y
#pragma unroll
    for (int i = 0; i < 4; ++i) {
        const int x = ty * 4 + i;
        uchar4 mk = *(const uchar4*)&mask[(((size_t)b * N + x) * N + a) * N + tx * 4];
        float4 o;
        o.x = mk.x ? -1000.0f : acc[i][0] * scale;
        o.y = mk.y ? -1000.0f : acc[i][1] * scale;
        o.z = mk.z ? -1000.0f : acc[i][2] * scale;
        o.w = mk.w ? -1000.0f : acc[i][3] * scale;
        *(float4*)&tile[x * 64 + tx * 4] = o;
    }
}

// ---------------------------------------------------------------------------
// Softmax over a (stride N*N in [b,h,a,x,y]). One thread per (x,y); 64 vals
// in registers, lane-coalesced. grid B*H*16, block 256.
// ---------------------------------------------------------------------------
__global__ __launch_bounds__(256) void softmax_a(float* __restrict__ att) {
    const int bh = blockIdx.x >> 4;
    const int chunk = blockIdx.x & 15;
    float* base = att + (size_t)bh * (N * N * N) + chunk * 256 + threadIdx.x;

    float v[64];
    float m = -1e30f;
#pragma unroll
    for (int a = 0; a < 64; ++a) {
        v[a] = base[(size_t)a * (N * N)];
        m = fmaxf(m, v[a]);
    }
    float s = 0.0f;
#pragma unroll
    for (int a = 0; a < 64; ++a) {
        v[a] = __expf(v[a] - m);
        s += v[a];
    }
    const float inv = 1.0f / s;
#pragma unroll
    for (int a = 0; a < 64; ++a) {
        base[(size_t)a * (N * N)] = v[a] * inv;
    }
}

// ---------------------------------------------------------------------------
// Combine: xbuf[b,x,y,h,d] = sum_a att[b,h,a,x,y]*LV[b,x,a,h,d]*RV[b,a,y,h,d]
// LV/RV from fused P (stride 1024). Output bf16 for the final MFMA GEMM.
// grid (4, 4, B*H): 16x x 16y tile, a-chunks of 8. block 256.
// ---------------------------------------------------------------------------
__global__ __launch_bounds__(256) void combine_kernel(const float* __restrict__ P,
                                                      const float* __restrict__ att,
                                                      ushort* __restrict__ xbuf) {
    const int LVSTRIDE = 8 * 32 + 8; // 264
    __shared__ __align__(16) float LVs[16 * 264];     // [x][a*32+d]
    __shared__ __align__(16) float RVs[8 * 16 * 32];  // [a][y][d]
    __shared__ __align__(16) float atts[16][132];     // [x][a*16+y]

    const int bh = blockIdx.z;
    const int b = bh >> 3, h = bh & 7;
    const int x0 = blockIdx.x * 16, y0 = blockIdx.y * 16;
    const int tid = threadIdx.x;
    const int x_l = tid >> 4, dp = tid & 15;

    float2 acc[16] = {};

    for (int ac = 0; ac < N; ac += 8) {
        __syncthreads();
        {
            int row = tid >> 1;
            int x = row >> 3, a = row & 7;
            int q0 = (tid & 1) * 16;
            const float* src = &P[(((size_t)b * N + x0 + x) * N + ac + a) * 1024 + OFF_LV + h * DK + q0];
            float* dst = &LVs[x * LVSTRIDE + a * 32 + q0];
#pragma unroll
            for (int q = 0; q < 4; ++q) *(float4*)&dst[q * 4] = *(const float4*)&src[q * 4];

            int aa = row >> 4, y = row & 15;
            const float* src2 = &P[(((size_t)b * N + ac + aa) * N + y0 + y) * 1024 + OFF_RV + h * DK + q0];
            float* dst2 = &RVs[(aa * 16 + y) * 32 + q0];
#pragma unroll
            for (int q = 0; q < 4; ++q) *(float4*)&dst2[q * 4] = *(const float4*)&src2[q * 4];

            int al = tid >> 5;          // 0..7
            int xl = (tid >> 1) & 15;   // 0..15
            int half = tid & 1;         // y offset 0 / 8
            const float* src3 = &att[(((size_t)bh * N + ac + al) * N + x0 + xl) * N + y0 + half * 8];
            float4 v0 = *(const float4*)&src3[0];
            float4 v1 = *(const float4*)&src3[4];
            *(float4*)&atts[xl][al * 16 + half * 8] = v0;
            *(float4*)&atts[xl][al * 16 + half * 8 + 4] = v1;
        }
        __syncthreads();

#pragma unroll
        for (int a = 0; a < 8; ++a) {
            float2 lv = *(const float2*)&LVs[x_l * LVSTRIDE + a * 32 + 2 * dp];
#pragma unroll
            for (int y = 0; y < 16; ++y) {
                float w = atts[x_l][a * 16 + y];
                float2 rv = *(const float2*)&RVs[(a * 16 + y) * 32 + 2 * dp];
                acc[y].x += (w * lv.x) * rv.x;
                acc[y].y += (w * lv.y) * rv.y;
            }
        }
    }

#pragma unroll
    for (int y = 0; y < 16; ++y) {
        ushort2 o = {f2b(acc[y].x), f2b(acc[y].y)};
        *(ushort2*)&xbuf[(((size_t)b * N + x0 + x_l) * N + y0 + y) * D + h * DK + 2 * dp] = o;
    }
}

// ---------------------------------------------------------------------------
extern "C" void kernel_launch(void* const* d_in, const int* in_sizes, int n_in,
                              void* d_out, int out_size, void* d_ws, size_t ws_size,
                              hipStream_t stream) {
    const float* state = (const float*)d_in[0];
    const unsigned char* mask = (const unsigned char*)d_in[1];
    const float* W_lk = (const float*)d_in[2];
    const float* b_lk = (const float*)d_in[3];
    const float* W_rk = (const float*)d_in[4];
    const float* b_rk = (const float*)d_in[5];
    const float* W_lv = (const float*)d_in[6];
    const float* b_lv = (const float*)d_in[7];
    const float* W_rv = (const float*)d_in[8];
    const float* b_rv = (const float*)d_in[9];
    const float* W_o = (const float*)d_in[10];
    const float* b_o = (const float*)d_in[11];
    float* out = (float*)d_out;

    char* ws = (char*)d_ws;
    float* P = (float*)ws;                               // 8192*1024 f32 = 33.5 MB
    ws += (size_t)M * 1024 * 4;
    float* att = (float*)ws;                             // 4,194,304 f32 = 16.8 MB
    ws += (size_t)B * H * N * N * N * 4;
    float* bias_cat = (float*)ws;                        // 1280 f32
    ws += 1280 * 4;
    ushort* state_bf = (ushort*)ws;                      // 2,097,152 bf16 = 4 MB
    ws += (size_t)M * D * 2;
    ushort* Wcat = (ushort*)ws;                          // 1280*256 bf16
    ws += (size_t)1280 * 256 * 2;
    ushort* xbuf_bf = (ushort*)ws;                       // 2,097,152 bf16 = 4 MB

    cast_all<<<2368, 256, 0, stream>>>(state, W_lk, W_rk, W_lv, W_rv, W_o,
                                       b_lk, b_rk, b_lv, b_rv, b_o,
                                       state_bf, Wcat, bias_cat);
    gemm_mfma<<<dim3(M / 128, 8), 256, 0, stream>>>(state_bf, Wcat, bias_cat, P, 1024);
    scores_kernel<<<dim3(N, H, B), 256, 0, stream>>>(P, mask, att);
    softmax_a<<<B * H * 16, 256, 0, stream>>>(att);
    combine_kernel<<<dim3(4, 4, B * H), 256, 0, stream>>>(P, att, xbuf_bf);
    gemm_mfma<<<dim3(M / 128, 2), 256, 0, stream>>>(xbuf_bf, Wcat + 1024 * 256, bias_cat + 1024, out, 256);
}

// Round 4
// 149.632 us; speedup vs baseline: 1.6448x; 1.0219x over previous
//
#include <hip/hip_runtime.h>

#define B 2
#define N 64
#define D 256
#define H 8
#define DK 32
#define M (B * N * N) // 8192

typedef __attribute__((ext_vector_type(8))) short bf16x8;
typedef __attribute__((ext_vector_type(4))) float f32x4;

// fused projection buffer column offsets (elements, row stride 1024)
#define OFF_LK 0
#define OFF_RK 256
#define OFF_LV 512
#define OFF_RV 768

__device__ __forceinline__ ushort f2b(float f) {
    union { float f; unsigned u; } v; v.f = f;
    unsigned r = v.u + 0x7fffu + ((v.u >> 16) & 1u); // RNE
    return (ushort)(r >> 16);
}
__device__ __forceinline__ float b2f(ushort u) {
    union { unsigned u; float f; } v; v.u = ((unsigned)u) << 16; return v.f;
}
// convert 8 bf16 (packed in a float4 register) to 8 floats
__device__ __forceinline__ void cvt8(float4 raw, float* f) {
    const ushort* s = (const ushort*)&raw;
#pragma unroll
    for (int j = 0; j < 8; ++j) f[j] = b2f(s[j]);
}

// ---------------------------------------------------------------------------
// Cast: state f32 -> bf16; 5 weights -> Wcat[1280][256] bf16; biases -> f32.
// ---------------------------------------------------------------------------
__global__ __launch_bounds__(256) void cast_all(const float* __restrict__ state,
                                                const float* __restrict__ W_lk, const float* __restrict__ W_rk,
                                                const float* __restrict__ W_lv, const float* __restrict__ W_rv,
                                                const float* __restrict__ W_o,
                                                const float* __restrict__ b_lk, const float* __restrict__ b_rk,
                                                const float* __restrict__ b_lv, const float* __restrict__ b_rv,
                                                const float* __restrict__ b_o,
                                                ushort* __restrict__ state_bf,
                                                ushort* __restrict__ Wcat,
                                                float* __restrict__ bias_cat) {
    const int gid = blockIdx.x * 256 + threadIdx.x;
    const float* Ws[5] = {W_lk, W_rk, W_lv, W_rv, W_o};
    const float* bs[5] = {b_lk, b_rk, b_lv, b_rv, b_o};

    if (gid < 1280) bias_cat[gid] = bs[gid >> 8][gid & 255];

    if (gid < 524288) {
        float4 v = *(const float4*)&state[(size_t)gid * 4];
        ushort4 o = {f2b(v.x), f2b(v.y), f2b(v.z), f2b(v.w)};
        *(ushort4*)&state_bf[(size_t)gid * 4] = o;
    } else {
        int u = gid - 524288;            // 0..81919
        int row = u >> 6;                // 0..1279
        int k4 = (u & 63) * 4;
        const float* W = Ws[row >> 8];
        float4 v = *(const float4*)&W[(size_t)(row & 255) * 256 + k4];
        ushort4 o = {f2b(v.x), f2b(v.y), f2b(v.z), f2b(v.w)};
        *(ushort4*)&Wcat[(size_t)row * 256 + k4] = o;
    }
}

// ---------------------------------------------------------------------------
// bf16 MFMA GEMM: C[rows, ldc] = A @ Bw^T + bias. 128x128 tile, 4 waves,
// 4x4 16x16x32 frags, BK=32. BF16OUT selects output dtype.
// ---------------------------------------------------------------------------
#define LDK 56

template <int BF16OUT>
__global__ __launch_bounds__(256) void gemm_mfma(const ushort* __restrict__ A,
                                                 const ushort* __restrict__ Bw,
                                                 const float* __restrict__ bias,
                                                 void* __restrict__ Cv, int ldc) {
    __shared__ __align__(16) ushort As[128 * LDK];
    __shared__ __align__(16) ushort Bs[128 * LDK];
    const int tid = threadIdx.x;
    const int lane = tid & 63;
    const int wave = tid >> 6;
    const int wm = (wave & 1) * 64;
    const int wn = (wave >> 1) * 64;
    const int row0 = blockIdx.x * 128;
    const int col0 = blockIdx.y * 128;

    const int srow = tid >> 2;
    const int skq = (tid & 3) * 8;

    const int fr = lane & 15;
    const int fk = (lane >> 4) * 8;

    f32x4 acc[4][4] = {};

    for (int k0 = 0; k0 < 256; k0 += 32) {
        float4 av0 = *(const float4*)&A[(size_t)(row0 + srow) * 256 + k0 + skq];
        float4 av1 = *(const float4*)&A[(size_t)(row0 + 64 + srow) * 256 + k0 + skq];
        float4 bv0 = *(const float4*)&Bw[(size_t)(col0 + srow) * 256 + k0 + skq];
        float4 bv1 = *(const float4*)&Bw[(size_t)(col0 + 64 + srow) * 256 + k0 + skq];
        __syncthreads();
        *(float4*)&As[srow * LDK + skq] = av0;
        *(float4*)&As[(64 + srow) * LDK + skq] = av1;
        *(float4*)&Bs[srow * LDK + skq] = bv0;
        *(float4*)&Bs[(64 + srow) * LDK + skq] = bv1;
        __syncthreads();

        bf16x8 af[4], bf[4];
#pragma unroll
        for (int i = 0; i < 4; ++i)
            af[i] = *(const bf16x8*)&As[(wm + i * 16 + fr) * LDK + fk];
#pragma unroll
        for (int j = 0; j < 4; ++j)
            bf[j] = *(const bf16x8*)&Bs[(wn + j * 16 + fr) * LDK + fk];
#pragma unroll
        for (int i = 0; i < 4; ++i)
#pragma unroll
            for (int j = 0; j < 4; ++j)
                acc[i][j] = __builtin_amdgcn_mfma_f32_16x16x32_bf16(af[i], bf[j], acc[i][j], 0, 0, 0);
    }

    // D[row][col]: row = (lane>>4)*4 + reg, col = lane&15
#pragma unroll
    for (int j = 0; j < 4; ++j) {
        const int col = col0 + wn + j * 16 + (lane & 15);
        const float bv = bias[col];
#pragma unroll
        for (int i = 0; i < 4; ++i) {
            const int rbase = row0 + wm + i * 16 + (lane >> 4) * 4;
#pragma unroll
            for (int r = 0; r < 4; ++r) {
                float o = acc[i][j][r] + bv;
                if (BF16OUT) ((ushort*)Cv)[(size_t)(rbase + r) * ldc + col] = f2b(o);
                else ((float*)Cv)[(size_t)(rbase + r) * ldc + col] = o;
            }
        }
    }
}

// ---------------------------------------------------------------------------
// Scores: per (a,h,b) block: scores[x,y] = sum_d LK[x,a,d]*RK[a,y,d] from
// bf16 P, masked+scaled, written bf16 to att[b,h,a,x,y] (contiguous tile).
// grid (N, H, B), block 256.
// ---------------------------------------------------------------------------
__global__ __launch_bounds__(256) void scores_kernel(const ushort* __restrict__ P,
                                                     const unsigned char* __restrict__ mask,
                                                     ushort* __restrict__ att) {
    const int a = blockIdx.x, h = blockIdx.y, b = blockIdx.z;
    __shared__ __align__(16) float LKs[DK][68]; // [d][x]
    __shared__ __align__(16) float RKs[DK][68]; // [d][y]
    const int tid = threadIdx.x;

    {
        const int x = tid >> 2;          // 0..63
        const int d0 = (tid & 3) * 8;    // 0,8,16,24
        float f[8];
        float4 v = *(const float4*)&P[(((size_t)b * N + x) * N + a) * 1024 + OFF_LK + h * DK + d0];
        cvt8(v, f);
#pragma unroll
        for (int j = 0; j < 8; ++j) LKs[d0 + j][x] = f[j];
        float4 w = *(const float4*)&P[(((size_t)b * N + a) * N + x) * 1024 + OFF_RK + h * DK + d0];
        cvt8(w, f);
#pragma unroll
        for (int j = 0; j < 8; ++j) RKs[d0 + j][x] = f[j];
    }
    __syncthreads();

    const int tx = tid & 15, ty = tid >> 4;
    float acc[4][4] = {};
#pragma unroll
    for (int d = 0; d < DK; ++d) {
        float4 xa = *(const float4*)&LKs[d][ty * 4];
        float4 yb = *(const float4*)&RKs[d][tx * 4];
        acc[0][0] += xa.x * yb.x; acc[0][1] += xa.x * yb.y; acc[0][2] += xa.x * yb.z; acc[0][3] += xa.x * yb.w;
        acc[1][0] += xa.y * yb.x; acc[1][1] += xa.y * yb.y; acc[1][2] += xa.y * yb.z; acc[1][3] += xa.y * yb.w;
        acc[2][0] += xa.z * yb.x; acc[2][1] += xa.z * yb.y; acc[2][2] += xa.z * yb.z; acc[2][3] += xa.z * yb.w;
        acc[3][0] += xa.w * yb.x; acc[3][1] += xa.w * yb.y; acc[3][2] += xa.w * yb.z; acc[3][3] += xa.w * yb.w;
    }

    const float scale = 0.17677669529663687f; // 1/sqrt(32)
    ushort* tile = &att[(((size_t)(b * H + h) * N + a) * N) * N]; // + x*64 + y
#pragma unroll
    for (int i = 0; i < 4; ++i) {
        const int x = ty * 4 + i;
        uchar4 mk = *(const uchar4*)&mask[(((size_t)b * N + x) * N + a) * N + tx * 4];
        ushort4 o;
        o.x = f2b(mk.x ? -1000.0f : acc[i][0] * scale);
        o.y = f2b(mk.y ? -1000.0f : acc[i][1] * scale);
        o.z = f2b(mk.z ? -1000.0f : acc[i][2] * scale);
        o.w = f2b(mk.w ? -1000.0f : acc[i][3] * scale);
        *(ushort4*)&tile[x * 64 + tx * 4] = o;
    }
}

// ---------------------------------------------------------------------------
// Softmax over a (stride N*N, bf16 in/out, fp32 math). One thread per (x,y).
// grid B*H*16, block 256.
// ---------------------------------------------------------------------------
__global__ __launch_bounds__(256) void softmax_a(ushort* __restrict__ att) {
    const int bh = blockIdx.x >> 4;
    const int chunk = blockIdx.x & 15;
    ushort* base = att + (size_t)bh * (N * N * N) + chunk * 256 + threadIdx.x;

    float v[64];
    float m = -1e30f;
#pragma unroll
    for (int a = 0; a < 64; ++a) {
        v[a] = b2f(base[(size_t)a * (N * N)]);
        m = fmaxf(m, v[a]);
    }
    float s = 0.0f;
#pragma unroll
    for (int a = 0; a < 64; ++a) {
        v[a] = __expf(v[a] - m);
        s += v[a];
    }
    const float inv = 1.0f / s;
#pragma unroll
    for (int a = 0; a < 64; ++a) {
        base[(size_t)a * (N * N)] = f2b(v[a] * inv);
    }
}

// ---------------------------------------------------------------------------
// Combine: xbuf[b,x,y,h,d] = sum_a att[b,h,a,x,y]*LV[x,a,d]*RV[a,y,d], bf16 out.
// grid (4,4,B*H), block 256. Thread = (x_l = tid>>4, dp = tid&15), loops 16 y.
// LDS layouts chosen for vectorized, broadcast-friendly, <=2-way-bank reads:
//   LVs2[a][x][dp]   float2, contiguous      -> 1 b64/thread/a, wave-contiguous
//   RVs2[a][dp][y18] float2, y padded to 18  -> 8 b128/thread/a, dp-stride 144B
//   atts[x][a][y20]  float,  y padded to 20  -> 4 b128/thread/a, broadcast in dp
// ---------------------------------------------------------------------------
__global__ __launch_bounds__(256) void combine_kernel(const ushort* __restrict__ P,
                                                      const ushort* __restrict__ att,
                                                      ushort* __restrict__ xbuf) {
    __shared__ __align__(16) float2 LVs2[8 * 16 * 16];  // [a][x][dp]
    __shared__ __align__(16) float2 RVs2[8 * 16 * 18];  // [a][dp][y(18)]
    __shared__ __align__(16) float atts[16 * 164];      // [x][a*20 + y]

    const int bh = blockIdx.z;
    const int b = bh >> 3, h = bh & 7;
    const int x0 = blockIdx.x * 16, y0 = blockIdx.y * 16;
    const int tid = threadIdx.x;
    const int x_l = tid >> 4, dp = tid & 15;

    float2 acc[16] = {};

    for (int ac = 0; ac < N; ac += 8) {
        __syncthreads();
        {
            const int r = tid >> 1, q = tid & 1;
            float f[16];
            // LV rows (x = r>>3, a = r&7): 32 bf16; this thread does 16 (q half)
            {
                int x = r >> 3, a = r & 7;
                const ushort* src = &P[(((size_t)b * N + x0 + x) * N + ac + a) * 1024 + OFF_LV + h * DK + q * 16];
                cvt8(*(const float4*)&src[0], f);
                cvt8(*(const float4*)&src[8], f + 8);
                float2* dst = &LVs2[(a * 16 + x) * 16 + q * 8];
#pragma unroll
                for (int j = 0; j < 4; ++j)
                    *(float4*)&dst[2 * j] = make_float4(f[4 * j], f[4 * j + 1], f[4 * j + 2], f[4 * j + 3]);
            }
            // RV rows (a = r>>4, y = r&15): transpose into [a][dp][y]
            {
                int a = r >> 4, y = r & 15;
                const ushort* src = &P[(((size_t)b * N + ac + a) * N + y0 + y) * 1024 + OFF_RV + h * DK + q * 16];
                cvt8(*(const float4*)&src[0], f);
                cvt8(*(const float4*)&src[8], f + 8);
#pragma unroll
                for (int m2 = 0; m2 < 8; ++m2)
                    RVs2[(a * 16 + q * 8 + m2) * 18 + y] = make_float2(f[2 * m2], f[2 * m2 + 1]);
            }
            // att rows (x = r>>3, a = r&7): 16 y bf16; q half of 8
            {
                int x = r >> 3, a = r & 7;
                const ushort* src = &att[(((size_t)bh * N + ac + a) * N + x0 + x) * N + y0 + q * 8];
                cvt8(*(const float4*)&src[0], f);
                float* dst = &atts[x * 164 + a * 20 + q * 8];
                *(float4*)&dst[0] = make_float4(f[0], f[1], f[2], f[3]);
                *(float4*)&dst[4] = make_float4(f[4], f[5], f[6], f[7]);
            }
        }
        __syncthreads();

#pragma unroll
        for (int a = 0; a < 8; ++a) {
            float2 lv = LVs2[(a * 16 + x_l) * 16 + dp];
            const float* wrow = &atts[x_l * 164 + a * 20];
            const float2* rvrow = &RVs2[(a * 16 + dp) * 18];
            float4 wq[4];
#pragma unroll
            for (int j = 0; j < 4; ++j) wq[j] = *(const float4*)&wrow[j * 4];
            const float* wv = (const float*)wq;
#pragma unroll
            for (int yq = 0; yq < 8; ++yq) {
                float4 rv4 = *(const float4*)&rvrow[yq * 2];
                float w0 = wv[yq * 2], w1 = wv[yq * 2 + 1];
                acc[yq * 2].x += (w0 * lv.x) * rv4.x;
                acc[yq * 2].y += (w0 * lv.y) * rv4.y;
                acc[yq * 2 + 1].x += (w1 * lv.x) * rv4.z;
                acc[yq * 2 + 1].y += (w1 * lv.y) * rv4.w;
            }
        }
    }

#pragma unroll
    for (int y = 0; y < 16; ++y) {
        ushort2 o = {f2b(acc[y].x), f2b(acc[y].y)};
        *(ushort2*)&xbuf[(((size_t)b * N + x0 + x_l) * N + y0 + y) * D + h * DK + 2 * dp] = o;
    }
}

// ---------------------------------------------------------------------------
extern "C" void kernel_launch(void* const* d_in, const int* in_sizes, int n_in,
                              void* d_out, int out_size, void* d_ws, size_t ws_size,
                              hipStream_t stream) {
    const float* state = (const float*)d_in[0];
    const unsigned char* mask = (const unsigned char*)d_in[1];
    const float* W_lk = (const float*)d_in[2];
    const float* b_lk = (const float*)d_in[3];
    const float* W_rk = (const float*)d_in[4];
    const float* b_rk = (const float*)d_in[5];
    const float* W_lv = (const float*)d_in[6];
    const float* b_lv = (const float*)d_in[7];
    const float* W_rv = (const float*)d_in[8];
    const float* b_rv = (const float*)d_in[9];
    const float* W_o = (const float*)d_in[10];
    const float* b_o = (const float*)d_in[11];
    float* out = (float*)d_out;

    char* ws = (char*)d_ws;
    ushort* P_bf = (ushort*)ws;                          // 8192*1024 bf16 = 16.8 MB
    ws += (size_t)M * 1024 * 2;
    ushort* att_bf = (ushort*)ws;                        // 4,194,304 bf16 = 8.4 MB
    ws += (size_t)B * H * N * N * N * 2;
    float* bias_cat = (float*)ws;                        // 1280 f32
    ws += 1280 * 4;
    ushort* state_bf = (ushort*)ws;                      // 4 MB
    ws += (size_t)M * D * 2;
    ushort* Wcat = (ushort*)ws;                          // 0.65 MB
    ws += (size_t)1280 * 256 * 2;
    ushort* xbuf_bf = (ushort*)ws;                       // 4 MB

    cast_all<<<2368, 256, 0, stream>>>(state, W_lk, W_rk, W_lv, W_rv, W_o,
                                       b_lk, b_rk, b_lv, b_rv, b_o,
                                       state_bf, Wcat, bias_cat);
    gemm_mfma<1><<<dim3(M / 128, 8), 256, 0, stream>>>(state_bf, Wcat, bias_cat, P_bf, 1024);
    scores_kernel<<<dim3(N, H, B), 256, 0, stream>>>(P_bf, mask, att_bf);
    softmax_a<<<B * H * 16, 256, 0, stream>>>(att_bf);
    combine_kernel<<<dim3(4, 4, B * H), 256, 0, stream>>>(P_bf, att_bf, xbuf_bf);
    gemm_mfma<0><<<dim3(M / 128, 2), 256, 0, stream>>>(xbuf_bf, Wcat + 1024 * 256, bias_cat + 1024, out, 256);
}

// Round 5
// 140.015 us; speedup vs baseline: 1.7578x; 1.0687x over previous
//
#include <hip/hip_runtime.h>

#define B 2
#define N 64
#define D 256
#define H 8
#define DK 32
#define M (B * N * N) // 8192

typedef __attribute__((ext_vector_type(8))) short bf16x8;
typedef __attribute__((ext_vector_type(4))) float f32x4;

// fused projection buffer column offsets (elements, row stride 1024)
#define OFF_LK 0
#define OFF_RK 256
#define OFF_LV 512
#define OFF_RV 768

__device__ __forceinline__ ushort f2b(float f) {
    union { float f; unsigned u; } v; v.f = f;
    unsigned r = v.u + 0x7fffu + ((v.u >> 16) & 1u); // RNE
    return (ushort)(r >> 16);
}
__device__ __forceinline__ float b2f(ushort u) {
    union { unsigned u; float f; } v; v.u = ((unsigned)u) << 16; return v.f;
}
// convert 8 bf16 (packed in a float4 register) to 8 floats
__device__ __forceinline__ void cvt8(float4 raw, float* f) {
    const ushort* s = (const ushort*)&raw;
#pragma unroll
    for (int j = 0; j < 8; ++j) f[j] = b2f(s[j]);
}

// async 16B/lane global->LDS (dst = wave-uniform base + lane*16)
__device__ __forceinline__ void glds16(const ushort* g, ushort* l) {
    __builtin_amdgcn_global_load_lds(
        (const __attribute__((address_space(1))) unsigned int*)g,
        (__attribute__((address_space(3))) unsigned int*)l, 16, 0, 0);
}

// ---------------------------------------------------------------------------
// Cast: state f32 -> bf16; 5 weights -> Wcat[1280][256] bf16; biases -> f32.
// ---------------------------------------------------------------------------
__global__ __launch_bounds__(256) void cast_all(const float* __restrict__ state,
                                                const float* __restrict__ W_lk, const float* __restrict__ W_rk,
                                                const float* __restrict__ W_lv, const float* __restrict__ W_rv,
                                                const float* __restrict__ W_o,
                                                const float* __restrict__ b_lk, const float* __restrict__ b_rk,
                                                const float* __restrict__ b_lv, const float* __restrict__ b_rv,
                                                const float* __restrict__ b_o,
                                                ushort* __restrict__ state_bf,
                                                ushort* __restrict__ Wcat,
                                                float* __restrict__ bias_cat) {
    const int gid = blockIdx.x * 256 + threadIdx.x;
    const float* Ws[5] = {W_lk, W_rk, W_lv, W_rv, W_o};
    const float* bs[5] = {b_lk, b_rk, b_lv, b_rv, b_o};

    if (gid < 1280) bias_cat[gid] = bs[gid >> 8][gid & 255];

    if (gid < 524288) {
        float4 v = *(const float4*)&state[(size_t)gid * 4];
        ushort4 o = {f2b(v.x), f2b(v.y), f2b(v.z), f2b(v.w)};
        *(ushort4*)&state_bf[(size_t)gid * 4] = o;
    } else {
        int u = gid - 524288;            // 0..81919
        int row = u >> 6;                // 0..1279
        int k4 = (u & 63) * 4;
        const float* W = Ws[row >> 8];
        float4 v = *(const float4*)&W[(size_t)(row & 255) * 256 + k4];
        ushort4 o = {f2b(v.x), f2b(v.y), f2b(v.z), f2b(v.w)};
        *(ushort4*)&Wcat[(size_t)row * 256 + k4] = o;
    }
}

// ---------------------------------------------------------------------------
// bf16 MFMA GEMM, m97-style: C[rows, ldc] = A @ Bw^T + bias. 128x128 tile,
// 4 waves, 4x4 16x16x32 frags, BK=32. Staging via global_load_lds width=16
// into UNPADDED LDS [row][32] (glds dst is wave-uniform base + lane*16).
// ---------------------------------------------------------------------------
template <int BF16OUT>
__global__ __launch_bounds__(256) void gemm_mfma(const ushort* __restrict__ A,
                                                 const ushort* __restrict__ Bw,
                                                 const float* __restrict__ bias,
                                                 void* __restrict__ Cv, int ldc) {
    __shared__ __align__(16) ushort As[128 * 32];
    __shared__ __align__(16) ushort Bs[128 * 32];
    const int tid = threadIdx.x;
    const int lane = tid & 63;
    const int wave = tid >> 6;
    const int wm = (wave & 1) * 64;
    const int wn = (wave >> 1) * 64;
    const int row0 = blockIdx.x * 128;
    const int col0 = blockIdx.y * 128;

    const int lr = lane >> 2;        // 0..15: row within 16-row segment
    const int lkq = (lane & 3) * 8;  // k element offset {0,8,16,24}

    // per-lane global bases; wave w stages rows [w*32, w*32+32)
    const ushort* gA0 = A + (size_t)(row0 + wave * 32 + lr) * 256 + lkq;
    const ushort* gA1 = gA0 + 16 * 256;
    const ushort* gB0 = Bw + (size_t)(col0 + wave * 32 + lr) * 256 + lkq;
    const ushort* gB1 = gB0 + 16 * 256;
    // wave-uniform LDS segment bases
    ushort* lA0 = &As[(wave * 32) * 32];
    ushort* lA1 = &As[(wave * 32 + 16) * 32];
    ushort* lB0 = &Bs[(wave * 32) * 32];
    ushort* lB1 = &Bs[(wave * 32 + 16) * 32];

    const int fr = lane & 15;
    const int fk = (lane >> 4) * 8;

    f32x4 acc[4][4] = {};

    for (int k0 = 0; k0 < 256; k0 += 32) {
        __syncthreads();                 // prior compute done before overwrite
        glds16(gA0 + k0, lA0);
        glds16(gA1 + k0, lA1);
        glds16(gB0 + k0, lB0);
        glds16(gB1 + k0, lB1);
        __syncthreads();                 // drains vmcnt before barrier

        bf16x8 af[4], bf[4];
#pragma unroll
        for (int i = 0; i < 4; ++i)
            af[i] = *(const bf16x8*)&As[(wm + i * 16 + fr) * 32 + fk];
#pragma unroll
        for (int j = 0; j < 4; ++j)
            bf[j] = *(const bf16x8*)&Bs[(wn + j * 16 + fr) * 32 + fk];
#pragma unroll
        for (int i = 0; i < 4; ++i)
#pragma unroll
            for (int j = 0; j < 4; ++j)
                acc[i][j] = __builtin_amdgcn_mfma_f32_16x16x32_bf16(af[i], bf[j], acc[i][j], 0, 0, 0);
    }

    // D[row][col]: row = (lane>>4)*4 + reg, col = lane&15
#pragma unroll
    for (int j = 0; j < 4; ++j) {
        const int col = col0 + wn + j * 16 + (lane & 15);
        const float bv = bias[col];
#pragma unroll
        for (int i = 0; i < 4; ++i) {
            const int rbase = row0 + wm + i * 16 + (lane >> 4) * 4;
#pragma unroll
            for (int r = 0; r < 4; ++r) {
                float o = acc[i][j][r] + bv;
                if (BF16OUT) ((ushort*)Cv)[(size_t)(rbase + r) * ldc + col] = f2b(o);
                else ((float*)Cv)[(size_t)(rbase + r) * ldc + col] = o;
            }
        }
    }
}

// ---------------------------------------------------------------------------
// Scores: per (a,h,b) block: scores[x,y] = sum_d LK[x,a,d]*RK[a,y,d] from
// bf16 P, masked+scaled, written bf16 RAW (pre-softmax) to att[b,h,a,x,y].
// grid (N, H, B), block 256.
// ---------------------------------------------------------------------------
__global__ __launch_bounds__(256) void scores_kernel(const ushort* __restrict__ P,
                                                     const unsigned char* __restrict__ mask,
                                                     ushort* __restrict__ att) {
    const int a = blockIdx.x, h = blockIdx.y, b = blockIdx.z;
    __shared__ __align__(16) float LKs[DK][68]; // [d][x]
    __shared__ __align__(16) float RKs[DK][68]; // [d][y]
    const int tid = threadIdx.x;

    {
        const int x = tid >> 2;          // 0..63
        const int d0 = (tid & 3) * 8;    // 0,8,16,24
        float f[8];
        float4 v = *(const float4*)&P[(((size_t)b * N + x) * N + a) * 1024 + OFF_LK + h * DK + d0];
        cvt8(v, f);
#pragma unroll
        for (int j = 0; j < 8; ++j) LKs[d0 + j][x] = f[j];
        float4 w = *(const float4*)&P[(((size_t)b * N + a) * N + x) * 1024 + OFF_RK + h * DK + d0];
        cvt8(w, f);
#pragma unroll
        for (int j = 0; j < 8; ++j) RKs[d0 + j][x] = f[j];
    }
    __syncthreads();

    const int tx = tid & 15, ty = tid >> 4;
    float acc[4][4] = {};
#pragma unroll
    for (int d = 0; d < DK; ++d) {
        float4 xa = *(const float4*)&LKs[d][ty * 4];
        float4 yb = *(const float4*)&RKs[d][tx * 4];
        acc[0][0] += xa.x * yb.x; acc[0][1] += xa.x * yb.y; acc[0][2] += xa.x * yb.z; acc[0][3] += xa.x * yb.w;
        acc[1][0] += xa.y * yb.x; acc[1][1] += xa.y * yb.y; acc[1][2] += xa.y * yb.z; acc[1][3] += xa.y * yb.w;
        acc[2][0] += xa.z * yb.x; acc[2][1] += xa.z * yb.y; acc[2][2] += xa.z * yb.z; acc[2][3] += xa.z * yb.w;
        acc[3][0] += xa.w * yb.x; acc[3][1] += xa.w * yb.y; acc[3][2] += xa.w * yb.z; acc[3][3] += xa.w * yb.w;
    }

    const float scale = 0.17677669529663687f; // 1/sqrt(32)
    ushort* tile = &att[(((size_t)(b * H + h) * N + a) * N) * N]; // + x*64 + y
#pragma unroll
    for (int i = 0; i < 4; ++i) {
        const int x = ty * 4 + i;
        uchar4 mk = *(const uchar4*)&mask[(((size_t)b * N + x) * N + a) * N + tx * 4];
        ushort4 o;
        o.x = f2b(mk.x ? -1000.0f : acc[i][0] * scale);
        o.y = f2b(mk.y ? -1000.0f : acc[i][1] * scale);
        o.z = f2b(mk.z ? -1000.0f : acc[i][2] * scale);
        o.w = f2b(mk.w ? -1000.0f : acc[i][3] * scale);
        *(ushort4*)&tile[x * 64 + tx * 4] = o;
    }
}

// ---------------------------------------------------------------------------
// Combine + ONLINE SOFTMAX over a:
//   xbuf[b,x,y,h,d] = (1/l) * sum_a exp(s[a]-m) * LV[x,a,d] * RV[a,y,d]
// att holds RAW scores [b,h,a,x,y] bf16. grid (4,4,B*H), block 256,
// a-chunks of 8. Per chunk: stage -> softmax sub-phase (thread=(x,y):
// chunk max, alpha, p in LDS) -> acc rescale + FMA loop. Epilogue /l.
// ---------------------------------------------------------------------------
__global__ __launch_bounds__(256) void combine_kernel(const ushort* __restrict__ P,
                                                      const ushort* __restrict__ att,
                                                      ushort* __restrict__ xbuf) {
    __shared__ __align__(16) float2 LVs2[8 * 16 * 16];  // [a][x][dp]
    __shared__ __align__(16) float2 RVs2[8 * 16 * 18];  // [a][dp][y(18)]
    __shared__ __align__(16) float atts[16 * 164];      // [x][a*20 + y]  (s -> p)
    __shared__ float mstate[16][17];
    __shared__ float lstate[16][17];
    __shared__ float alphas[16][17];

    const int bh = blockIdx.z;
    const int b = bh >> 3, h = bh & 7;
    const int x0 = blockIdx.x * 16, y0 = blockIdx.y * 16;
    const int tid = threadIdx.x;
    const int x_l = tid >> 4, dp = tid & 15;

    // online-softmax state init (owned by thread (x_l, dp) as (x, y))
    mstate[x_l][dp] = -3.0e38f;
    lstate[x_l][dp] = 0.0f;

    float2 acc[16] = {};

    for (int ac = 0; ac < N; ac += 8) {
        __syncthreads();
        {
            const int r = tid >> 1, q = tid & 1;
            float f[16];
            // LV rows (x = r>>3, a = r&7): 32 bf16; this thread does 16 (q half)
            {
                int x = r >> 3, a = r & 7;
                const ushort* src = &P[(((size_t)b * N + x0 + x) * N + ac + a) * 1024 + OFF_LV + h * DK + q * 16];
                cvt8(*(const float4*)&src[0], f);
                cvt8(*(const float4*)&src[8], f + 8);
                float2* dst = &LVs2[(a * 16 + x) * 16 + q * 8];
#pragma unroll
                for (int j = 0; j < 4; ++j)
                    *(float4*)&dst[2 * j] = make_float4(f[4 * j], f[4 * j + 1], f[4 * j + 2], f[4 * j + 3]);
            }
            // RV rows (a = r>>4, y = r&15): transpose into [a][dp][y]
            {
                int a = r >> 4, y = r & 15;
                const ushort* src = &P[(((size_t)b * N + ac + a) * N + y0 + y) * 1024 + OFF_RV + h * DK + q * 16];
                cvt8(*(const float4*)&src[0], f);
                cvt8(*(const float4*)&src[8], f + 8);
#pragma unroll
                for (int m2 = 0; m2 < 8; ++m2)
                    RVs2[(a * 16 + q * 8 + m2) * 18 + y] = make_float2(f[2 * m2], f[2 * m2 + 1]);
            }
            // att rows (x = r>>3, a = r&7): 16 y bf16 RAW scores; q half of 8
            {
                int x = r >> 3, a = r & 7;
                const ushort* src = &att[(((size_t)bh * N + ac + a) * N + x0 + x) * N + y0 + q * 8];
                cvt8(*(const float4*)&src[0], f);
                float* dst = &atts[x * 164 + a * 20 + q * 8];
                *(float4*)&dst[0] = make_float4(f[0], f[1], f[2], f[3]);
                *(float4*)&dst[4] = make_float4(f[4], f[5], f[6], f[7]);
            }
        }
        __syncthreads();

        // --- softmax sub-phase: thread (sx = x_l, sy = dp) owns (x, y) ---
        {
            const int sx = x_l, sy = dp;
            float s8[8];
#pragma unroll
            for (int a = 0; a < 8; ++a) s8[a] = atts[sx * 164 + a * 20 + sy];
            float mc = s8[0];
#pragma unroll
            for (int a = 1; a < 8; ++a) mc = fmaxf(mc, s8[a]);
            const float mold = mstate[sx][sy];
            const float mnew = fmaxf(mold, mc);
            const float alpha = __expf(mold - mnew);   // 0 on first chunk
            float ps = 0.0f;
#pragma unroll
            for (int a = 0; a < 8; ++a) {
                float p = __expf(s8[a] - mnew);
                atts[sx * 164 + a * 20 + sy] = p;
                ps += p;
            }
            lstate[sx][sy] = lstate[sx][sy] * alpha + ps;
            mstate[sx][sy] = mnew;
            alphas[sx][sy] = alpha;
        }
        __syncthreads();

        // --- rescale accumulators by this chunk's alpha ---
#pragma unroll
        for (int y = 0; y < 16; ++y) {
            float al = alphas[x_l][y];
            acc[y].x *= al; acc[y].y *= al;
        }

        // --- accumulate chunk ---
#pragma unroll
        for (int a = 0; a < 8; ++a) {
            float2 lv = LVs2[(a * 16 + x_l) * 16 + dp];
            const float* wrow = &atts[x_l * 164 + a * 20];
            const float2* rvrow = &RVs2[(a * 16 + dp) * 18];
            float4 wq[4];
#pragma unroll
            for (int j = 0; j < 4; ++j) wq[j] = *(const float4*)&wrow[j * 4];
            const float* wv = (const float*)wq;
#pragma unroll
            for (int yq = 0; yq < 8; ++yq) {
                float4 rv4 = *(const float4*)&rvrow[yq * 2];
                float w0 = wv[yq * 2], w1 = wv[yq * 2 + 1];
                acc[yq * 2].x += (w0 * lv.x) * rv4.x;
                acc[yq * 2].y += (w0 * lv.y) * rv4.y;
                acc[yq * 2 + 1].x += (w1 * lv.x) * rv4.z;
                acc[yq * 2 + 1].y += (w1 * lv.y) * rv4.w;
            }
        }
    }

#pragma unroll
    for (int y = 0; y < 16; ++y) {
        const float invl = 1.0f / lstate[x_l][y];
        ushort2 o = {f2b(acc[y].x * invl), f2b(acc[y].y * invl)};
        *(ushort2*)&xbuf[(((size_t)b * N + x0 + x_l) * N + y0 + y) * D + h * DK + 2 * dp] = o;
    }
}

// ---------------------------------------------------------------------------
extern "C" void kernel_launch(void* const* d_in, const int* in_sizes, int n_in,
                              void* d_out, int out_size, void* d_ws, size_t ws_size,
                              hipStream_t stream) {
    const float* state = (const float*)d_in[0];
    const unsigned char* mask = (const unsigned char*)d_in[1];
    const float* W_lk = (const float*)d_in[2];
    const float* b_lk = (const float*)d_in[3];
    const float* W_rk = (const float*)d_in[4];
    const float* b_rk = (const float*)d_in[5];
    const float* W_lv = (const float*)d_in[6];
    const float* b_lv = (const float*)d_in[7];
    const float* W_rv = (const float*)d_in[8];
    const float* b_rv = (const float*)d_in[9];
    const float* W_o = (const float*)d_in[10];
    const float* b_o = (const float*)d_in[11];
    float* out = (float*)d_out;

    char* ws = (char*)d_ws;
    ushort* P_bf = (ushort*)ws;                          // 8192*1024 bf16 = 16.8 MB
    ws += (size_t)M * 1024 * 2;
    ushort* att_bf = (ushort*)ws;                        // raw scores, 8.4 MB
    ws += (size_t)B * H * N * N * N * 2;
    float* bias_cat = (float*)ws;                        // 1280 f32
    ws += 1280 * 4;
    ushort* state_bf = (ushort*)ws;                      // 4 MB
    ws += (size_t)M * D * 2;
    ushort* Wcat = (ushort*)ws;                          // 0.65 MB
    ws += (size_t)1280 * 256 * 2;
    ushort* xbuf_bf = (ushort*)ws;                       // 4 MB

    cast_all<<<2368, 256, 0, stream>>>(state, W_lk, W_rk, W_lv, W_rv, W_o,
                                       b_lk, b_rk, b_lv, b_rv, b_o,
                                       state_bf, Wcat, bias_cat);
    gemm_mfma<1><<<dim3(M / 128, 8), 256, 0, stream>>>(state_bf, Wcat, bias_cat, P_bf, 1024);
    scores_kernel<<<dim3(N, H, B), 256, 0, stream>>>(P_bf, mask, att_bf);
    combine_kernel<<<dim3(4, 4, B * H), 256, 0, stream>>>(P_bf, att_bf, xbuf_bf);
    gemm_mfma<0><<<dim3(M / 128, 2), 256, 0, stream>>>(xbuf_bf, Wcat + 1024 * 256, bias_cat + 1024, out, 256);
}

// Round 6
// 133.721 us; speedup vs baseline: 1.8405x; 1.0471x over previous
//
#include <hip/hip_runtime.h>

#define B 2
#define N 64
#define D 256
#define H 8
#define DK 32
#define M (B * N * N) // 8192

typedef __attribute__((ext_vector_type(8))) short bf16x8;
typedef __attribute__((ext_vector_type(4))) float f32x4;

// fused projection buffer column offsets (elements, row stride 1024)
#define OFF_LK 0
#define OFF_RK 256
#define OFF_LV 512
#define OFF_RV 768

__device__ __forceinline__ ushort f2b(float f) {
    union { float f; unsigned u; } v; v.f = f;
    unsigned r = v.u + 0x7fffu + ((v.u >> 16) & 1u); // RNE
    return (ushort)(r >> 16);
}
__device__ __forceinline__ float b2f(ushort u) {
    union { unsigned u; float f; } v; v.u = ((unsigned)u) << 16; return v.f;
}
// convert 8 bf16 (packed in a float4 register) to 8 floats
__device__ __forceinline__ void cvt8(float4 raw, float* f) {
    const ushort* s = (const ushort*)&raw;
#pragma unroll
    for (int j = 0; j < 8; ++j) f[j] = b2f(s[j]);
}

// async 16B/lane global->LDS (dst = wave-uniform base + lane*16)
__device__ __forceinline__ void glds16(const ushort* g, ushort* l) {
    __builtin_amdgcn_global_load_lds(
        (const __attribute__((address_space(1))) unsigned int*)g,
        (__attribute__((address_space(3))) unsigned int*)l, 16, 0, 0);
}

// ---------------------------------------------------------------------------
// Cast: state f32 -> bf16; 5 weights -> Wcat[1280][256] bf16; biases -> f32.
// ---------------------------------------------------------------------------
__global__ __launch_bounds__(256) void cast_all(const float* __restrict__ state,
                                                const float* __restrict__ W_lk, const float* __restrict__ W_rk,
                                                const float* __restrict__ W_lv, const float* __restrict__ W_rv,
                                                const float* __restrict__ W_o,
                                                const float* __restrict__ b_lk, const float* __restrict__ b_rk,
                                                const float* __restrict__ b_lv, const float* __restrict__ b_rv,
                                                const float* __restrict__ b_o,
                                                ushort* __restrict__ state_bf,
                                                ushort* __restrict__ Wcat,
                                                float* __restrict__ bias_cat) {
    const int gid = blockIdx.x * 256 + threadIdx.x;
    const float* Ws[5] = {W_lk, W_rk, W_lv, W_rv, W_o};
    const float* bs[5] = {b_lk, b_rk, b_lv, b_rv, b_o};

    if (gid < 1280) bias_cat[gid] = bs[gid >> 8][gid & 255];

    if (gid < 524288) {
        float4 v = *(const float4*)&state[(size_t)gid * 4];
        ushort4 o = {f2b(v.x), f2b(v.y), f2b(v.z), f2b(v.w)};
        *(ushort4*)&state_bf[(size_t)gid * 4] = o;
    } else {
        int u = gid - 524288;            // 0..81919
        int row = u >> 6;                // 0..1279
        int k4 = (u & 63) * 4;
        const float* W = Ws[row >> 8];
        float4 v = *(const float4*)&W[(size_t)(row & 255) * 256 + k4];
        ushort4 o = {f2b(v.x), f2b(v.y), f2b(v.z), f2b(v.w)};
        *(ushort4*)&Wcat[(size_t)row * 256 + k4] = o;
    }
}

// ---------------------------------------------------------------------------
// bf16 MFMA GEMM, m97-style: C[rows, ldc] = A @ Bw^T + bias. 128x128 tile,
// 4 waves, 4x4 16x16x32 frags, BK=32. Staging via global_load_lds width=16.
// ---------------------------------------------------------------------------
template <int BF16OUT>
__global__ __launch_bounds__(256) void gemm_mfma(const ushort* __restrict__ A,
                                                 const ushort* __restrict__ Bw,
                                                 const float* __restrict__ bias,
                                                 void* __restrict__ Cv, int ldc) {
    __shared__ __align__(16) ushort As[128 * 32];
    __shared__ __align__(16) ushort Bs[128 * 32];
    const int tid = threadIdx.x;
    const int lane = tid & 63;
    const int wave = tid >> 6;
    const int wm = (wave & 1) * 64;
    const int wn = (wave >> 1) * 64;
    const int row0 = blockIdx.x * 128;
    const int col0 = blockIdx.y * 128;

    const int lr = lane >> 2;        // 0..15
    const int lkq = (lane & 3) * 8;  // {0,8,16,24}

    const ushort* gA0 = A + (size_t)(row0 + wave * 32 + lr) * 256 + lkq;
    const ushort* gA1 = gA0 + 16 * 256;
    const ushort* gB0 = Bw + (size_t)(col0 + wave * 32 + lr) * 256 + lkq;
    const ushort* gB1 = gB0 + 16 * 256;
    ushort* lA0 = &As[(wave * 32) * 32];
    ushort* lA1 = &As[(wave * 32 + 16) * 32];
    ushort* lB0 = &Bs[(wave * 32) * 32];
    ushort* lB1 = &Bs[(wave * 32 + 16) * 32];

    const int fr = lane & 15;
    const int fk = (lane >> 4) * 8;

    f32x4 acc[4][4] = {};

    for (int k0 = 0; k0 < 256; k0 += 32) {
        __syncthreads();
        glds16(gA0 + k0, lA0);
        glds16(gA1 + k0, lA1);
        glds16(gB0 + k0, lB0);
        glds16(gB1 + k0, lB1);
        __syncthreads();

        bf16x8 af[4], bf[4];
#pragma unroll
        for (int i = 0; i < 4; ++i)
            af[i] = *(const bf16x8*)&As[(wm + i * 16 + fr) * 32 + fk];
#pragma unroll
        for (int j = 0; j < 4; ++j)
            bf[j] = *(const bf16x8*)&Bs[(wn + j * 16 + fr) * 32 + fk];
#pragma unroll
        for (int i = 0; i < 4; ++i)
#pragma unroll
            for (int j = 0; j < 4; ++j)
                acc[i][j] = __builtin_amdgcn_mfma_f32_16x16x32_bf16(af[i], bf[j], acc[i][j], 0, 0, 0);
    }

#pragma unroll
    for (int j = 0; j < 4; ++j) {
        const int col = col0 + wn + j * 16 + (lane & 15);
        const float bv = bias[col];
#pragma unroll
        for (int i = 0; i < 4; ++i) {
            const int rbase = row0 + wm + i * 16 + (lane >> 4) * 4;
#pragma unroll
            for (int r = 0; r < 4; ++r) {
                float o = acc[i][j][r] + bv;
                if (BF16OUT) ((ushort*)Cv)[(size_t)(rbase + r) * ldc + col] = f2b(o);
                else ((float*)Cv)[(size_t)(rbase + r) * ldc + col] = o;
            }
        }
    }
}

// ---------------------------------------------------------------------------
// FUSED scores + online-softmax + gated combine.
// Per block: tile (x0..x0+15, y0..y0+15) of (b,h). Loop a-chunks of 8:
//   1) stage LK/RK (raw bf16), LV/RV (f32, transposed), mask tile.
//   2) scores: one mfma_16x16x32_bf16 per a per wave (wave w does a=2w,2w+1);
//      masked+scaled into atts[a][x][y] (f32).
//   3) softmax sub-phase: thread (x,y) updates m/l, writes p into atts.
//   4) gate: thread tile (4x, 4y, 2d): acc[i][j] (+= p * LV ⊙ RV), alpha-rescaled.
// Epilogue: /l, bf16 store. grid (4,4,B*H), block 256.
// ---------------------------------------------------------------------------
__global__ __launch_bounds__(256) void fused_attn(const ushort* __restrict__ P,
                                                  const unsigned char* __restrict__ mask,
                                                  ushort* __restrict__ xbuf) {
    __shared__ __align__(16) ushort LKs[8 * 16 * 40];   // [a][x][d(40 pad)] bf16
    __shared__ __align__(16) ushort RKs[8 * 16 * 40];   // [a][y][d]
    __shared__ __align__(16) float2 LVs[8 * 16 * 18];   // [a][dp][x(18 pad)]
    __shared__ __align__(16) float2 RVs[8 * 16 * 18];   // [a][dp][y(18 pad)]
    __shared__ __align__(16) float atts[8 * 16 * 20];   // [a][x][y(20 pad)] s -> p
    __shared__ __align__(16) unsigned char masks[16 * 8 * 16]; // [x][a][y]
    __shared__ float mstate[16 * 20];
    __shared__ float lstate[16 * 20];
    __shared__ float alphas[16 * 20];

    const int bh = blockIdx.z;
    const int b = bh >> 3, h = bh & 7;
    const int x0 = blockIdx.x * 16, y0 = blockIdx.y * 16;
    const int tid = threadIdx.x;
    const int lane = tid & 63, wave = tid >> 6;

    // gating coords: tid = (xg*4+yg)*16 + dp
    const int xg = tid >> 6, yg = (tid >> 4) & 3, dp = tid & 15;
    // softmax coords
    const int sx = tid >> 4, sy = tid & 15;

    mstate[sx * 20 + sy] = -3.0e38f;
    lstate[sx * 20 + sy] = 0.0f;

    float2 acc[4][4] = {};
    const float scale = 0.17677669529663687f; // 1/sqrt(32)

    for (int ac = 0; ac < N; ac += 8) {
        __syncthreads();
        // ---- stage ----
        {
            const int r = tid >> 1, q = tid & 1;
            const int xs = r >> 3, as = r & 7;           // (x, a) for LK/LV/att-mask rows
            const int ar = r >> 4, yr = r & 15;          // (a, y) for RK/RV rows
            // LK raw bf16: 16 bf16 (q half of 32)
            {
                const ushort* s = &P[(((size_t)b * N + x0 + xs) * N + ac + as) * 1024 + OFF_LK + h * DK + q * 16];
                *(float4*)&LKs[(as * 16 + xs) * 40 + q * 16]     = *(const float4*)&s[0];
                *(float4*)&LKs[(as * 16 + xs) * 40 + q * 16 + 8] = *(const float4*)&s[8];
            }
            // RK raw bf16
            {
                const ushort* s = &P[(((size_t)b * N + ac + ar) * N + y0 + yr) * 1024 + OFF_RK + h * DK + q * 16];
                *(float4*)&RKs[(ar * 16 + yr) * 40 + q * 16]     = *(const float4*)&s[0];
                *(float4*)&RKs[(ar * 16 + yr) * 40 + q * 16 + 8] = *(const float4*)&s[8];
            }
            float f[16];
            // LV f32 transposed: LVs[a][dp = q*8+m][x]
            {
                const ushort* s = &P[(((size_t)b * N + x0 + xs) * N + ac + as) * 1024 + OFF_LV + h * DK + q * 16];
                cvt8(*(const float4*)&s[0], f);
                cvt8(*(const float4*)&s[8], f + 8);
#pragma unroll
                for (int m2 = 0; m2 < 8; ++m2)
                    LVs[(as * 16 + q * 8 + m2) * 18 + xs] = make_float2(f[2 * m2], f[2 * m2 + 1]);
            }
            // RV f32 transposed: RVs[a][dp][y]
            {
                const ushort* s = &P[(((size_t)b * N + ac + ar) * N + y0 + yr) * 1024 + OFF_RV + h * DK + q * 16];
                cvt8(*(const float4*)&s[0], f);
                cvt8(*(const float4*)&s[8], f + 8);
#pragma unroll
                for (int m2 = 0; m2 < 8; ++m2)
                    RVs[(ar * 16 + q * 8 + m2) * 18 + yr] = make_float2(f[2 * m2], f[2 * m2 + 1]);
            }
            // mask tile: threads 0..127 load 16 bytes (one (x,a) row of y)
            if (tid < 128) {
                const int xm = tid >> 3, am = tid & 7;
                const unsigned char* s = &mask[(((size_t)b * N + x0 + xm) * N + ac + am) * N + y0];
                *(int4*)&masks[(xm * 8 + am) * 16] = *(const int4*)s;
            }
        }
        __syncthreads();

        // ---- scores via MFMA: wave handles a = 2*wave, 2*wave+1 ----
        {
            const int fr = lane & 15;
            const int fkq = (lane >> 4) * 8;
            const int yq = lane & 15, xq = (lane >> 4) * 4;
#pragma unroll
            for (int aw = 0; aw < 2; ++aw) {
                const int a = wave * 2 + aw;
                bf16x8 af = *(const bf16x8*)&LKs[(a * 16 + fr) * 40 + fkq];
                bf16x8 bfv = *(const bf16x8*)&RKs[(a * 16 + fr) * 40 + fkq];
                f32x4 s = {};
                s = __builtin_amdgcn_mfma_f32_16x16x32_bf16(af, bfv, s, 0, 0, 0);
#pragma unroll
                for (int rr = 0; rr < 4; ++rr) {
                    const int x = xq + rr;
                    float sv = s[rr] * scale;
                    if (masks[(x * 8 + a) * 16 + yq]) sv = -1000.0f;
                    atts[(a * 16 + x) * 20 + yq] = sv;
                }
            }
        }
        __syncthreads();

        // ---- online softmax sub-phase: thread (sx, sy) ----
        {
            float s8[8];
#pragma unroll
            for (int a = 0; a < 8; ++a) s8[a] = atts[(a * 16 + sx) * 20 + sy];
            float mc = s8[0];
#pragma unroll
            for (int a = 1; a < 8; ++a) mc = fmaxf(mc, s8[a]);
            const float mold = mstate[sx * 20 + sy];
            const float mnew = fmaxf(mold, mc);
            const float alpha = __expf(mold - mnew);
            float ps = 0.0f;
#pragma unroll
            for (int a = 0; a < 8; ++a) {
                float p = __expf(s8[a] - mnew);
                atts[(a * 16 + sx) * 20 + sy] = p;
                ps += p;
            }
            lstate[sx * 20 + sy] = lstate[sx * 20 + sy] * alpha + ps;
            mstate[sx * 20 + sy] = mnew;
            alphas[sx * 20 + sy] = alpha;
        }
        __syncthreads();

        // ---- rescale + gate: thread tile (4x, 4y, 2d) ----
        {
#pragma unroll
            for (int i = 0; i < 4; ++i) {
                float4 av = *(const float4*)&alphas[(xg * 4 + i) * 20 + yg * 4];
                const float* ap = (const float*)&av;
#pragma unroll
                for (int j = 0; j < 4; ++j) {
                    acc[i][j].x *= ap[j];
                    acc[i][j].y *= ap[j];
                }
            }
#pragma unroll
            for (int a = 0; a < 8; ++a) {
                float4 lq0 = *(const float4*)&LVs[(a * 16 + dp) * 18 + xg * 4];
                float4 lq1 = *(const float4*)&LVs[(a * 16 + dp) * 18 + xg * 4 + 2];
                float4 rq0 = *(const float4*)&RVs[(a * 16 + dp) * 18 + yg * 4];
                float4 rq1 = *(const float4*)&RVs[(a * 16 + dp) * 18 + yg * 4 + 2];
                float2 lv[4] = {make_float2(lq0.x, lq0.y), make_float2(lq0.z, lq0.w),
                                make_float2(lq1.x, lq1.y), make_float2(lq1.z, lq1.w)};
                float2 rv[4] = {make_float2(rq0.x, rq0.y), make_float2(rq0.z, rq0.w),
                                make_float2(rq1.x, rq1.y), make_float2(rq1.z, rq1.w)};
#pragma unroll
                for (int i = 0; i < 4; ++i) {
                    float4 at = *(const float4*)&atts[(a * 16 + xg * 4 + i) * 20 + yg * 4];
                    const float* wp = (const float*)&at;
#pragma unroll
                    for (int j = 0; j < 4; ++j) {
                        acc[i][j].x += (wp[j] * lv[i].x) * rv[j].x;
                        acc[i][j].y += (wp[j] * lv[i].y) * rv[j].y;
                    }
                }
            }
        }
    }

    // ---- epilogue: divide by l, store bf16 ----
#pragma unroll
    for (int i = 0; i < 4; ++i) {
        float4 lq = *(const float4*)&lstate[(xg * 4 + i) * 20 + yg * 4];
        const float* lp = (const float*)&lq;
#pragma unroll
        for (int j = 0; j < 4; ++j) {
            const float invl = 1.0f / lp[j];
            ushort2 o = {f2b(acc[i][j].x * invl), f2b(acc[i][j].y * invl)};
            *(ushort2*)&xbuf[(((size_t)b * N + x0 + xg * 4 + i) * N + y0 + yg * 4 + j) * D + h * DK + 2 * dp] = o;
        }
    }
}

// ---------------------------------------------------------------------------
extern "C" void kernel_launch(void* const* d_in, const int* in_sizes, int n_in,
                              void* d_out, int out_size, void* d_ws, size_t ws_size,
                              hipStream_t stream) {
    const float* state = (const float*)d_in[0];
    const unsigned char* mask = (const unsigned char*)d_in[1];
    const float* W_lk = (const float*)d_in[2];
    const float* b_lk = (const float*)d_in[3];
    const float* W_rk = (const float*)d_in[4];
    const float* b_rk = (const float*)d_in[5];
    const float* W_lv = (const float*)d_in[6];
    const float* b_lv = (const float*)d_in[7];
    const float* W_rv = (const float*)d_in[8];
    const float* b_rv = (const float*)d_in[9];
    const float* W_o = (const float*)d_in[10];
    const float* b_o = (const float*)d_in[11];
    float* out = (float*)d_out;

    char* ws = (char*)d_ws;
    ushort* P_bf = (ushort*)ws;                          // 8192*1024 bf16 = 16.8 MB
    ws += (size_t)M * 1024 * 2;
    float* bias_cat = (float*)ws;                        // 1280 f32
    ws += 1280 * 4;
    ushort* state_bf = (ushort*)ws;                      // 4 MB
    ws += (size_t)M * D * 2;
    ushort* Wcat = (ushort*)ws;                          // 0.65 MB
    ws += (size_t)1280 * 256 * 2;
    ushort* xbuf_bf = (ushort*)ws;                       // 4 MB

    cast_all<<<2368, 256, 0, stream>>>(state, W_lk, W_rk, W_lv, W_rv, W_o,
                                       b_lk, b_rk, b_lv, b_rv, b_o,
                                       state_bf, Wcat, bias_cat);
    gemm_mfma<1><<<dim3(M / 128, 8), 256, 0, stream>>>(state_bf, Wcat, bias_cat, P_bf, 1024);
    fused_attn<<<dim3(4, 4, B * H), 256, 0, stream>>>(P_bf, mask, xbuf_bf);
    gemm_mfma<0><<<dim3(M / 128, 2), 256, 0, stream>>>(xbuf_bf, Wcat + 1024 * 256, bias_cat + 1024, out, 256);
}